// Round 3
// baseline (694.959 us; speedup 1.0000x reference)
//
#include <hip/hip_runtime.h>
#include <math.h>

// =============================================================================
// ROUND 3 = ATTRIBUTION PROBE. Each kernel launched with redundant duplicate
// blocks (x16 / x8) so its per-dispatch duration exceeds the ~44us harness
// fillBuffer dispatches and surfaces in the rocprof top-5 with full counters.
// All duplicate work is idempotent (same-value writes). Next round reverts
// multiplicities to 1 and attacks the dominant kernel.
// =============================================================================

#define T_SEQ   2048
#define EDIM    512
#define NHEADS  8
#define DHEAD   64
#define BATCH   4
#define WIN     128
#define TOPK    96

typedef _Float16 f16;
typedef f16 f16x2 __attribute__((ext_vector_type(2)));
typedef f16 f16x4 __attribute__((ext_vector_type(4)));
typedef f16 f16x8 __attribute__((ext_vector_type(8)));
typedef float f32x4 __attribute__((ext_vector_type(4)));

#define GLD_LDS(gp, lp) \
    __builtin_amdgcn_global_load_lds((const __attribute__((address_space(1))) void*)(gp), \
                                     (__attribute__((address_space(3))) void*)(lp), 16, 0, 0)

// ---------------------------------------------------------------------------
// fp32 -> f16 conversion. PROBE: x16 duplicate grid.
// ---------------------------------------------------------------------------
__global__ __launch_bounds__(256) void convert_all(
    const float* __restrict__ x,  const float* __restrict__ wq,
    const float* __restrict__ wk, const float* __restrict__ wv,
    const float* __restrict__ wo,
    f16* __restrict__ xh, f16* __restrict__ wqkvh, f16* __restrict__ woh)
{
    long i = ((long)(blockIdx.x % 5120) * 256 + threadIdx.x) * 4;
    const float* src; f16* dst; long off;
    if      (i < 4194304L) { src = x;  dst = xh;             off = i;            }
    else if (i < 4456448L) { src = wq; dst = wqkvh;          off = i - 4194304L; }
    else if (i < 4718592L) { src = wk; dst = wqkvh + 262144; off = i - 4456448L; }
    else if (i < 4980736L) { src = wv; dst = wqkvh + 524288; off = i - 4718592L; }
    else                   { src = wo; dst = woh;            off = i - 4980736L; }
    float4 v = *(const float4*)(src + off);
    f16x4 h; h.x = (f16)v.x; h.y = (f16)v.y; h.z = (f16)v.z; h.w = (f16)v.w;
    *(f16x4*)(dst + off) = h;
}

// ---------------------------------------------------------------------------
// QKV f16 MFMA GEMM. PROBE: blockIdx.z in [0,8) ignored (x8 duplicates).
// ---------------------------------------------------------------------------
__global__ __launch_bounds__(256) void gemm_qkv(
    const f16* __restrict__ A, const f16* __restrict__ W,
    const float* __restrict__ b0, const float* __restrict__ b1,
    const float* __restrict__ b2,
    f16* __restrict__ cq, f16* __restrict__ ck, f16* __restrict__ cv)
{
    __shared__ f16 SH[16384];
    f16* Ash = SH;
    f16* Bsh = SH + 8192;

    const int tid  = threadIdx.x;
    const int w    = tid >> 6;
    const int lane = tid & 63;
    const int m0   = blockIdx.x * 128;
    const int n0   = blockIdx.y * 128;
    const int K    = 512;
    const int lr   = lane & 15;
    const int lk8  = (lane >> 4) * 8;

    f32x4 acc[4][4];
#pragma unroll
    for (int i = 0; i < 4; i++)
#pragma unroll
        for (int j = 0; j < 4; j++) acc[i][j] = (f32x4){0.f, 0.f, 0.f, 0.f};

    const int wmi = (w & 1) * 4;
    const int wni = (w >> 1) * 4;

    for (int k0 = 0; k0 < K; k0 += 64) {
#pragma unroll
        for (int cc = 0; cc < 4; cc++) {
            const int c  = w * 4 + cc;
            const int ms = c & 7, kp = c >> 3;
            const int kcol = k0 + kp * 32 + lk8;
            GLD_LDS(A + (size_t)(m0 + ms * 16 + lr) * K + kcol, Ash + c * 512);
            GLD_LDS(W + (size_t)(n0 + ms * 16 + lr) * K + kcol, Bsh + c * 512);
        }
        __syncthreads();

#pragma unroll
        for (int kp = 0; kp < 2; kp++) {
            f16x8 af[4], bf[4];
#pragma unroll
            for (int i = 0; i < 4; i++)
                af[i] = *(const f16x8*)(Ash + (kp * 8 + wmi + i) * 512 + lane * 8);
#pragma unroll
            for (int j = 0; j < 4; j++)
                bf[j] = *(const f16x8*)(Bsh + (kp * 8 + wni + j) * 512 + lane * 8);
#pragma unroll
            for (int i = 0; i < 4; i++)
#pragma unroll
                for (int j = 0; j < 4; j++)
                    acc[i][j] = __builtin_amdgcn_mfma_f32_16x16x32_f16(af[i], bf[j], acc[i][j], 0, 0, 0);
        }
        __syncthreads();
    }

    const int quad = lane >> 4;
    const int mat  = n0 >> 9;
    const float* bias = (mat == 0) ? b0 : ((mat == 1) ? b1 : b2);
    const int bb  = m0 >> 11;
    const int t0  = m0 & (T_SEQ - 1);
    const int hh0 = (n0 & 511) >> 6;

    if (mat < 2) {
#pragma unroll
        for (int i = 0; i < 4; i++) {
#pragma unroll
            for (int j = 0; j < 4; j++) {
                const int nl = (w >> 1) * 64 + j * 16 + lr;
                const float bvv = bias[(n0 & 511) + nl];
#pragma unroll
                for (int r = 0; r < 4; r++) {
                    const int ml = (w & 1) * 64 + i * 16 + quad * 4 + r;
                    SH[ml * 128 + (nl ^ (((ml >> 2) & 7) << 4))] = (f16)(acc[i][j][r] + bvv);
                }
            }
        }
        __syncthreads();
        f16* dst = (mat == 0) ? cq : ck;
#pragma unroll
        for (int s = 0; s < 8; s++) {
            const int c   = tid + 256 * s;
            const int row = c >> 4;
            const int nt  = (c & 15) * 8;
            const f16x8 vv = *(const f16x8*)&SH[row * 128 + (nt ^ (((row >> 2) & 7) << 4))];
            const int hh = hh0 + (nt >> 6);
            const int dd = nt & 63;
            *(f16x8*)(dst + ((size_t)((bb * NHEADS + hh) * T_SEQ) + t0 + row) * 64 + dd) = vv;
        }
    } else {
#pragma unroll
        for (int i = 0; i < 4; i++) {
#pragma unroll
            for (int j = 0; j < 4; j++) {
                const int nl = (w >> 1) * 64 + j * 16 + lr;
                const float bvv = bias[(n0 & 511) + nl];
                const int mlb = (w & 1) * 64 + i * 16 + quad * 4;
                f16x4 pk;
#pragma unroll
                for (int r = 0; r < 4; r++) pk[r] = (f16)(acc[i][j][r] + bvv);
                *(f16x4*)&SH[nl * 128 + ((mlb + 8 * (nl & 15)) & 127)] = pk;
            }
        }
        __syncthreads();
#pragma unroll
        for (int s = 0; s < 8; s++) {
            const int c    = tid + 256 * s;
            const int nrow = c >> 4;
            const int cht  = c & 15;
            const int chl  = (cht + (nrow & 15)) & 15;
            const f16x8 vv = *(const f16x8*)&SH[nrow * 128 + chl * 8];
            const int hh = hh0 + (nrow >> 6);
            const int dd = nrow & 63;
            *(f16x8*)(cv + ((size_t)((bb * NHEADS + hh) * 64 + dd)) * T_SEQ + t0 + cht * 8) = vv;
        }
    }
}

// ---------------------------------------------------------------------------
// Output-projection GEMM. PROBE: blockIdx.z ignored (x8 duplicates).
// ---------------------------------------------------------------------------
__global__ __launch_bounds__(256) void gemm_o(
    const f16* __restrict__ A, const f16* __restrict__ W,
    const float* __restrict__ bias, float* __restrict__ C)
{
    __shared__ __align__(16) char SMO[34816];
    f16*   Ash = (f16*)SMO;
    f16*   Bsh = (f16*)(SMO + 16384);
    float* SC  = (float*)SMO;

    const int tid  = threadIdx.x;
    const int w    = tid >> 6;
    const int lane = tid & 63;
    const int m0   = blockIdx.x * 128;
    const int n0   = blockIdx.y * 64;
    const int lr   = lane & 15;
    const int lk8  = (lane >> 4) * 8;

    f32x4 acc[4][2];
#pragma unroll
    for (int i = 0; i < 4; i++)
#pragma unroll
        for (int j = 0; j < 2; j++) acc[i][j] = (f32x4){0.f, 0.f, 0.f, 0.f};

    for (int k0 = 0; k0 < 512; k0 += 64) {
#pragma unroll
        for (int cc = 0; cc < 4; cc++) {
            const int c  = w * 4 + cc;
            const int ms = c & 7, kp = c >> 3;
            GLD_LDS(A + (size_t)(m0 + ms * 16 + lr) * 512 + k0 + kp * 32 + lk8, Ash + c * 512);
        }
#pragma unroll
        for (int cc = 0; cc < 2; cc++) {
            const int c  = w * 2 + cc;
            const int ns = c & 3, kp = c >> 2;
            GLD_LDS(W + (size_t)(n0 + ns * 16 + lr) * 512 + k0 + kp * 32 + lk8, Bsh + c * 512);
        }
        __syncthreads();

#pragma unroll
        for (int kp = 0; kp < 2; kp++) {
            f16x8 af[4], bf[2];
#pragma unroll
            for (int i = 0; i < 4; i++)
                af[i] = *(const f16x8*)(Ash + (kp * 8 + (w & 1) * 4 + i) * 512 + lane * 8);
#pragma unroll
            for (int j = 0; j < 2; j++)
                bf[j] = *(const f16x8*)(Bsh + (kp * 4 + (w >> 1) * 2 + j) * 512 + lane * 8);
#pragma unroll
            for (int i = 0; i < 4; i++)
#pragma unroll
                for (int j = 0; j < 2; j++)
                    acc[i][j] = __builtin_amdgcn_mfma_f32_16x16x32_f16(af[i], bf[j], acc[i][j], 0, 0, 0);
        }
        __syncthreads();
    }

    const int quad = lane >> 4;
#pragma unroll
    for (int i = 0; i < 4; i++) {
#pragma unroll
        for (int j = 0; j < 2; j++) {
            const int n  = (w >> 1) * 32 + j * 16 + lr;
            const float bv = bias[n0 + n];
#pragma unroll
            for (int r = 0; r < 4; r++) {
                const int m = (w & 1) * 64 + i * 16 + quad * 4 + r;
                SC[m * 68 + n] = acc[i][j][r] + bv;
            }
        }
    }
    __syncthreads();
#pragma unroll
    for (int s = 0; s < 8; s++) {
        const int c   = tid + 256 * s;
        const int row = c >> 4;
        const int nt  = (c & 15) * 4;
        const f32x4 vv = *(const f32x4*)&SC[row * 68 + nt];
        *(f32x4*)&C[(size_t)(m0 + row) * 512 + n0 + nt] = vv;
    }
}

// ---------------------------------------------------------------------------
// Attention v5. PROBE: blockIdx.z ignored (x8 duplicates).
// ---------------------------------------------------------------------------
__global__ __launch_bounds__(512, 4) void attn_v5(
    const f16* __restrict__ qh, const f16* __restrict__ kh,
    const f16* __restrict__ vtg, const float* __restrict__ logsig,
    f16* __restrict__ abh)
{
    __shared__ __align__(16) char smem[79616];
    f16*   Qs   = (f16*)smem;                 // [64][88]
    f16*   Ks   = (f16*)(smem + 11264);       // [192][88]
    f16*   P    = (f16*)smem;                 // [64][216] alias Qs/Ks
    float* Sc   = (float*)(smem + 45056);     // [64][132]
    f16*   Vt   = (f16*)(smem + 45056);       // [64][216] alias Sc
    float* ksqs = (float*)(smem + 78848);     // [192]

    const int tid = threadIdx.x, w = tid >> 6, lane = tid & 63;
    const int lr = lane & 15, quad = lane >> 4;
    const int q0 = blockIdx.x * 64, bh = blockIdx.y;
    const int h = bh & 7, b = bh >> 3;
    const size_t tb = (size_t)bh * T_SEQ;
    const int ks0 = q0 - 128;

    // ---- phase 1: stage Q, K (+fused |k|^2) ----
    {
        const int row = tid >> 3, ch = tid & 7;
        f16x8 v = *(const f16x8*)(qh + (tb + q0 + row) * 64 + ch * 8);
        *(f16x8*)(Qs + row * 88 + ch * 8) = v;
    }
#pragma unroll
    for (int s = 0; s < 3; s++) {
        const int i = tid + 512 * s;
        const int row = i >> 3, ch = i & 7;
        const int kg = ks0 + row;
        f16x8 v = {};
        if (kg >= 0) v = *(const f16x8*)(kh + (tb + kg) * 64 + ch * 8);
        *(f16x8*)(Ks + row * 88 + ch * 8) = v;
        float ps = 0.f;
#pragma unroll
        for (int j = 0; j < 8; j++) { const float fv = (float)v[j]; ps += fv * fv; }
        ps += __shfl_xor(ps, 1);
        ps += __shfl_xor(ps, 2);
        ps += __shfl_xor(ps, 4);
        if (ch == 0) ksqs[row] = ps;
    }
    __syncthreads();

    // ---- phase 2: QK^T ----
    const int mt  = w & 3;
    const int kh2 = w >> 2;
    f32x4 accQ[6];
#pragma unroll
    for (int jt = 0; jt < 6; jt++) accQ[jt] = (f32x4){0.f, 0.f, 0.f, 0.f};

    __builtin_amdgcn_s_setprio(1);
#pragma unroll
    for (int kp = 0; kp < 2; kp++) {
        const f16x8 af = *(const f16x8*)(Qs + (mt * 16 + lr) * 88 + kp * 32 + quad * 8);
#pragma unroll
        for (int jt = 0; jt < 6; jt++) {
            const f16x8 bf = *(const f16x8*)(Ks + (kh2 * 96 + jt * 16 + lr) * 88 + kp * 32 + quad * 8);
            accQ[jt] = __builtin_amdgcn_mfma_f32_16x16x32_f16(af, bf, accQ[jt], 0, 0, 0);
        }
    }
    __builtin_amdgcn_s_setprio(0);
    const float inv_s2 = __expf(-2.0f * logsig[h]);
#pragma unroll
    for (int jt = 0; jt < 6; jt++) {
        const int c  = kh2 * 96 + jt * 16 + lr;
        const float kq = ksqs[c];
        const int kg = ks0 + c;
#pragma unroll
        for (int r = 0; r < 4; r++) {
            const int dq = mt * 16 + quad * 4 + r;
            const unsigned wc = (unsigned)(c - dq - 1);
            if (wc < 128u) {
                Sc[dq * 132 + wc] = (kg >= 0) ? (accQ[jt][r] - 0.5f * kq) * inv_s2
                                              : -INFINITY;
            }
        }
    }

    // ---- T14: issue V^T global loads now; LDS write deferred ----
    f16x8 vpre[3];
#pragma unroll
    for (int s = 0; s < 3; s++) {
        const int i = tid + 512 * s;
        const int d = i / 24, ch = i % 24;
        const int t0v = ks0 + ch * 8;
        f16x8 vv = {};
        if (t0v >= 0) vv = *(const f16x8*)(vtg + ((size_t)bh * 64 + d) * T_SEQ + t0v);
        vpre[s] = vv;
    }
    __syncthreads();

    // ---- phase 3: exact top-96 via ballot binary search ----
    const int wq8 = w * 8;
#pragma unroll 1
    for (int g = 0; g < 2; g++) {
        const int dq0 = wq8 + g * 4;
        float s0[4], s1[4], m[4];
        unsigned u0[4], u1[4], t[4];
#pragma unroll
        for (int qq = 0; qq < 4; qq++) {
            const int dq = dq0 + qq;
            s0[qq] = Sc[dq * 132 + lane];
            s1[qq] = Sc[dq * 132 + 64 + lane];
            const unsigned b0 = __float_as_uint(s0[qq]);
            const unsigned b1 = __float_as_uint(s1[qq]);
            u0[qq] = b0 ^ (unsigned)(((int)b0 >> 31) | 0x80000000);
            u1[qq] = b1 ^ (unsigned)(((int)b1 >> 31) | 0x80000000);
            m[qq] = __uint_as_float(__builtin_amdgcn_readlane(__float_as_uint(s1[qq]), 63));
            t[qq] = 0u;
        }
#pragma unroll
        for (int bit = 31; bit >= 0; bit--) {
#pragma unroll
            for (int qq = 0; qq < 4; qq++) {
                const unsigned c = t[qq] | (1u << bit);
                const int n = __popcll(__ballot(u0[qq] >= c)) +
                              __popcll(__ballot(u1[qq] >= c));
                if (n >= TOPK) t[qq] = c;
            }
        }
#pragma unroll
        for (int qq = 0; qq < 4; qq++) {
            const int dq = dq0 + qq;
            const float p0 = (u0[qq] >= t[qq]) ? __expf(s0[qq] - m[qq]) : 0.f;
            const float p1 = (u1[qq] >= t[qq]) ? __expf(s1[qq] - m[qq]) : 0.f;
            P[dq * 216 + dq + 1 + lane]  = (f16)p0;
            P[dq * 216 + dq + 65 + lane] = (f16)p1;
            P[dq * 216 + ((lane <= dq) ? lane : lane + 128)] = (f16)0.f;
        }
    }
    __syncthreads();

    // ---- phase 4: write prefetched V^T ----
#pragma unroll
    for (int s = 0; s < 3; s++) {
        const int i = tid + 512 * s;
        const int d = i / 24, ch = i % 24;
        *(f16x8*)(Vt + d * 216 + ch * 8) = vpre[s];
    }
    __syncthreads();

    // ---- phase 5: PV MFMA + ones-MFMA row sums ----
    const int nh = w >> 2;
    f32x4 accO[2];
#pragma unroll
    for (int nt = 0; nt < 2; nt++) accO[nt] = (f32x4){0.f, 0.f, 0.f, 0.f};
    f32x4 accS = (f32x4){0.f, 0.f, 0.f, 0.f};
    f16x8 onesf;
#pragma unroll
    for (int j = 0; j < 8; j++) onesf[j] = (f16)1.0f;

    __builtin_amdgcn_s_setprio(1);
#pragma unroll
    for (int ks = 0; ks < 6; ks++) {
        const f16x8 pf = *(const f16x8*)(P + (mt * 16 + lr) * 216 + ks * 32 + quad * 8);
#pragma unroll
        for (int nt = 0; nt < 2; nt++) {
            const f16x8 vf = *(const f16x8*)(Vt + (nh * 32 + nt * 16 + lr) * 216 + ks * 32 + quad * 8);
            accO[nt] = __builtin_amdgcn_mfma_f32_16x16x32_f16(pf, vf, accO[nt], 0, 0, 0);
        }
        accS = __builtin_amdgcn_mfma_f32_16x16x32_f16(pf, onesf, accS, 0, 0, 0);
    }
    __builtin_amdgcn_s_setprio(0);
    float inv[4];
#pragma unroll
    for (int r = 0; r < 4; r++) inv[r] = 1.0f / accS[r];

#pragma unroll
    for (int nt = 0; nt < 2; nt++) {
        const int d = nh * 32 + nt * 16 + lr;
#pragma unroll
        for (int r = 0; r < 4; r++) {
            const int q = q0 + mt * 16 + quad * 4 + r;
            abh[((size_t)(b * T_SEQ + q)) * 512 + h * 64 + d] = (f16)(accO[nt][r] * inv[r]);
        }
    }
}

// ---------------------------------------------------------------------------
extern "C" void kernel_launch(void* const* d_in, const int* in_sizes, int n_in,
                              void* d_out, int out_size, void* d_ws, size_t ws_size,
                              hipStream_t stream)
{
    const float* x      = (const float*)d_in[0];
    const float* Wq     = (const float*)d_in[1];
    const float* bq     = (const float*)d_in[2];
    const float* Wk     = (const float*)d_in[3];
    const float* bk     = (const float*)d_in[4];
    const float* Wv     = (const float*)d_in[5];
    const float* bv     = (const float*)d_in[6];
    const float* Wo     = (const float*)d_in[7];
    const float* bo     = (const float*)d_in[8];
    const float* logsig = (const float*)d_in[9];

    f16* xh    = (f16*)d_ws;              // 4,194,304
    f16* wqkvh = xh + 4194304;            // 786,432
    f16* woh   = wqkvh + 786432;          // 262,144
    f16* qh    = woh + 262144;            // 4,194,304  [B,H,T,64]
    f16* kh    = qh + 4194304;            // 4,194,304  [B,H,T,64]
    f16* vtg   = kh + 4194304;            // 4,194,304  [B,H,64,T]
    f16* abh   = xh;                      // alias: x dead after QKV GEMM

    // PROBE multiplicities: convert x16, qkv x8, attn x8, gemm_o x8.
    convert_all<<<5120 * 16, 256, 0, stream>>>(x, Wq, Wk, Wv, Wo, xh, wqkvh, woh);

    gemm_qkv<<<dim3(64, 12, 8), 256, 0, stream>>>(xh, wqkvh, bq, bk, bv, qh, kh, vtg);

    attn_v5<<<dim3(T_SEQ / 64, BATCH * NHEADS, 8), 512, 0, stream>>>(
        qh, kh, vtg, logsig, abh);

    gemm_o<<<dim3(64, 8, 8), 256, 0, stream>>>(abh, woh, bo, (float*)d_out);
}

// Round 4
// 192.225 us; speedup vs baseline: 3.6153x; 3.6153x over previous
//
#include <hip/hip_runtime.h>
#include <math.h>

#define T_SEQ   2048
#define EDIM    512
#define NHEADS  8
#define DHEAD   64
#define BATCH   4
#define WIN     128
#define TOPK    96

typedef _Float16 f16;
typedef f16 f16x2 __attribute__((ext_vector_type(2)));
typedef f16 f16x4 __attribute__((ext_vector_type(4)));
typedef f16 f16x8 __attribute__((ext_vector_type(8)));
typedef float f32x4 __attribute__((ext_vector_type(4)));

#define GLD_LDS(gp, lp) \
    __builtin_amdgcn_global_load_lds((const __attribute__((address_space(1))) void*)(gp), \
                                     (__attribute__((address_space(3))) void*)(lp), 16, 0, 0)

// ---------------------------------------------------------------------------
// fp32 -> f16 conversion of x, Wq, Wk, Wv, Wo. 4 elems/thread.
// ---------------------------------------------------------------------------
__global__ __launch_bounds__(256) void convert_all(
    const float* __restrict__ x,  const float* __restrict__ wq,
    const float* __restrict__ wk, const float* __restrict__ wv,
    const float* __restrict__ wo,
    f16* __restrict__ xh, f16* __restrict__ wqkvh, f16* __restrict__ woh)
{
    long i = ((long)blockIdx.x * 256 + threadIdx.x) * 4;
    const float* src; f16* dst; long off;
    if      (i < 4194304L) { src = x;  dst = xh;             off = i;            }
    else if (i < 4456448L) { src = wq; dst = wqkvh;          off = i - 4194304L; }
    else if (i < 4718592L) { src = wk; dst = wqkvh + 262144; off = i - 4456448L; }
    else if (i < 4980736L) { src = wv; dst = wqkvh + 524288; off = i - 4718592L; }
    else                   { src = wo; dst = woh;            off = i - 4980736L; }
    float4 v = *(const float4*)(src + off);
    f16x4 h; h.x = (f16)v.x; h.y = (f16)v.y; h.z = (f16)v.z; h.w = (f16)v.w;
    *(f16x4*)(dst + off) = h;
}

// ---------------------------------------------------------------------------
// QKV f16 MFMA GEMM (m97-pattern): 128x128 tile, BK=64, 256 threads.
// ---------------------------------------------------------------------------
__global__ __launch_bounds__(256) void gemm_qkv(
    const f16* __restrict__ A, const f16* __restrict__ W,
    const float* __restrict__ b0, const float* __restrict__ b1,
    const float* __restrict__ b2,
    f16* __restrict__ cq, f16* __restrict__ ck, f16* __restrict__ cv)
{
    __shared__ f16 SH[16384];
    f16* Ash = SH;
    f16* Bsh = SH + 8192;

    const int tid  = threadIdx.x;
    const int w    = tid >> 6;
    const int lane = tid & 63;
    const int m0   = blockIdx.x * 128;
    const int n0   = blockIdx.y * 128;
    const int K    = 512;
    const int lr   = lane & 15;
    const int lk8  = (lane >> 4) * 8;

    f32x4 acc[4][4];
#pragma unroll
    for (int i = 0; i < 4; i++)
#pragma unroll
        for (int j = 0; j < 4; j++) acc[i][j] = (f32x4){0.f, 0.f, 0.f, 0.f};

    const int wmi = (w & 1) * 4;
    const int wni = (w >> 1) * 4;

    for (int k0 = 0; k0 < K; k0 += 64) {
#pragma unroll
        for (int cc = 0; cc < 4; cc++) {
            const int c  = w * 4 + cc;
            const int ms = c & 7, kp = c >> 3;
            const int kcol = k0 + kp * 32 + lk8;
            GLD_LDS(A + (size_t)(m0 + ms * 16 + lr) * K + kcol, Ash + c * 512);
            GLD_LDS(W + (size_t)(n0 + ms * 16 + lr) * K + kcol, Bsh + c * 512);
        }
        __syncthreads();

#pragma unroll
        for (int kp = 0; kp < 2; kp++) {
            f16x8 af[4], bf[4];
#pragma unroll
            for (int i = 0; i < 4; i++)
                af[i] = *(const f16x8*)(Ash + (kp * 8 + wmi + i) * 512 + lane * 8);
#pragma unroll
            for (int j = 0; j < 4; j++)
                bf[j] = *(const f16x8*)(Bsh + (kp * 8 + wni + j) * 512 + lane * 8);
#pragma unroll
            for (int i = 0; i < 4; i++)
#pragma unroll
                for (int j = 0; j < 4; j++)
                    acc[i][j] = __builtin_amdgcn_mfma_f32_16x16x32_f16(af[i], bf[j], acc[i][j], 0, 0, 0);
        }
        __syncthreads();
    }

    const int quad = lane >> 4;
    const int mat  = n0 >> 9;
    const float* bias = (mat == 0) ? b0 : ((mat == 1) ? b1 : b2);
    const int bb  = m0 >> 11;
    const int t0  = m0 & (T_SEQ - 1);
    const int hh0 = (n0 & 511) >> 6;

    if (mat < 2) {
#pragma unroll
        for (int i = 0; i < 4; i++) {
#pragma unroll
            for (int j = 0; j < 4; j++) {
                const int nl = (w >> 1) * 64 + j * 16 + lr;
                const float bvv = bias[(n0 & 511) + nl];
#pragma unroll
                for (int r = 0; r < 4; r++) {
                    const int ml = (w & 1) * 64 + i * 16 + quad * 4 + r;
                    SH[ml * 128 + (nl ^ (((ml >> 2) & 7) << 4))] = (f16)(acc[i][j][r] + bvv);
                }
            }
        }
        __syncthreads();
        f16* dst = (mat == 0) ? cq : ck;
#pragma unroll
        for (int s = 0; s < 8; s++) {
            const int c   = tid + 256 * s;
            const int row = c >> 4;
            const int nt  = (c & 15) * 8;
            const f16x8 vv = *(const f16x8*)&SH[row * 128 + (nt ^ (((row >> 2) & 7) << 4))];
            const int hh = hh0 + (nt >> 6);
            const int dd = nt & 63;
            *(f16x8*)(dst + ((size_t)((bb * NHEADS + hh) * T_SEQ) + t0 + row) * 64 + dd) = vv;
        }
    } else {
#pragma unroll
        for (int i = 0; i < 4; i++) {
#pragma unroll
            for (int j = 0; j < 4; j++) {
                const int nl = (w >> 1) * 64 + j * 16 + lr;
                const float bvv = bias[(n0 & 511) + nl];
                const int mlb = (w & 1) * 64 + i * 16 + quad * 4;
                f16x4 pk;
#pragma unroll
                for (int r = 0; r < 4; r++) pk[r] = (f16)(acc[i][j][r] + bvv);
                *(f16x4*)&SH[nl * 128 + ((mlb + 8 * (nl & 15)) & 127)] = pk;
            }
        }
        __syncthreads();
#pragma unroll
        for (int s = 0; s < 8; s++) {
            const int c    = tid + 256 * s;
            const int nrow = c >> 4;
            const int cht  = c & 15;
            const int chl  = (cht + (nrow & 15)) & 15;
            const f16x8 vv = *(const f16x8*)&SH[nrow * 128 + chl * 8];
            const int hh = hh0 + (nrow >> 6);
            const int dd = nrow & 63;
            *(f16x8*)(cv + ((size_t)((bb * NHEADS + hh) * 64 + dd)) * T_SEQ + t0 + cht * 8) = vv;
        }
    }
}

// ---------------------------------------------------------------------------
// Output-projection GEMM: 128x64 tile, BK=64, 256 threads -> 512 blocks.
// LDS-transposed epilogue (stride-68 fp32 tile), coalesced f32x4 stores.
// ---------------------------------------------------------------------------
__global__ __launch_bounds__(256) void gemm_o(
    const f16* __restrict__ A, const f16* __restrict__ W,
    const float* __restrict__ bias, float* __restrict__ C)
{
    __shared__ __align__(16) char SMO[34816];
    f16*   Ash = (f16*)SMO;
    f16*   Bsh = (f16*)(SMO + 16384);
    float* SC  = (float*)SMO;

    const int tid  = threadIdx.x;
    const int w    = tid >> 6;
    const int lane = tid & 63;
    const int m0   = blockIdx.x * 128;
    const int n0   = blockIdx.y * 64;
    const int lr   = lane & 15;
    const int lk8  = (lane >> 4) * 8;

    f32x4 acc[4][2];
#pragma unroll
    for (int i = 0; i < 4; i++)
#pragma unroll
        for (int j = 0; j < 2; j++) acc[i][j] = (f32x4){0.f, 0.f, 0.f, 0.f};

    for (int k0 = 0; k0 < 512; k0 += 64) {
#pragma unroll
        for (int cc = 0; cc < 4; cc++) {
            const int c  = w * 4 + cc;
            const int ms = c & 7, kp = c >> 3;
            GLD_LDS(A + (size_t)(m0 + ms * 16 + lr) * 512 + k0 + kp * 32 + lk8, Ash + c * 512);
        }
#pragma unroll
        for (int cc = 0; cc < 2; cc++) {
            const int c  = w * 2 + cc;
            const int ns = c & 3, kp = c >> 2;
            GLD_LDS(W + (size_t)(n0 + ns * 16 + lr) * 512 + k0 + kp * 32 + lk8, Bsh + c * 512);
        }
        __syncthreads();

#pragma unroll
        for (int kp = 0; kp < 2; kp++) {
            f16x8 af[4], bf[2];
#pragma unroll
            for (int i = 0; i < 4; i++)
                af[i] = *(const f16x8*)(Ash + (kp * 8 + (w & 1) * 4 + i) * 512 + lane * 8);
#pragma unroll
            for (int j = 0; j < 2; j++)
                bf[j] = *(const f16x8*)(Bsh + (kp * 4 + (w >> 1) * 2 + j) * 512 + lane * 8);
#pragma unroll
            for (int i = 0; i < 4; i++)
#pragma unroll
                for (int j = 0; j < 2; j++)
                    acc[i][j] = __builtin_amdgcn_mfma_f32_16x16x32_f16(af[i], bf[j], acc[i][j], 0, 0, 0);
        }
        __syncthreads();
    }

    const int quad = lane >> 4;
#pragma unroll
    for (int i = 0; i < 4; i++) {
#pragma unroll
        for (int j = 0; j < 2; j++) {
            const int n  = (w >> 1) * 32 + j * 16 + lr;
            const float bv = bias[n0 + n];
#pragma unroll
            for (int r = 0; r < 4; r++) {
                const int m = (w & 1) * 64 + i * 16 + quad * 4 + r;
                SC[m * 68 + n] = acc[i][j][r] + bv;
            }
        }
    }
    __syncthreads();
#pragma unroll
    for (int s = 0; s < 8; s++) {
        const int c   = tid + 256 * s;
        const int row = c >> 4;
        const int nt  = (c & 15) * 4;
        const f32x4 vv = *(const f32x4*)&SC[row * 68 + nt];
        *(f32x4*)&C[(size_t)(m0 + row) * 512 + n0 + nt] = vv;
    }
}

// ---------------------------------------------------------------------------
// Attention v6: LDS 79.6KB -> 50.8KB via time-multiplexed regions
//   -> 3 blocks/CU (24 waves/CU, 75% occupancy, was 50%).
// Regions: [0,11264) Qs | [11264,45056) Ks | then Sc aliases [0,33792) after
// MFMA barrier | then P [0,25600) + Vt [25600,51200) after score-reads are
// hoisted to registers | ksqs at [51200,51968).
// P/Vt stride 216 -> 200 (MFMA A-frag reads reach col 191 max).
// Vt LDS writes + P zero-fill overlap the register-resident top-k search.
// ---------------------------------------------------------------------------
__device__ __forceinline__ float keyinv(unsigned u)
{
    // inverse of the order-preserving f32->u32 key transform
    unsigned b = u ^ ((unsigned)((int)(~u) >> 31) | 0x80000000u);
    return __uint_as_float(b);
}

__global__ __launch_bounds__(512, 6) void attn_v6(
    const f16* __restrict__ qh, const f16* __restrict__ kh,
    const f16* __restrict__ vtg, const float* __restrict__ logsig,
    f16* __restrict__ abh)
{
    __shared__ __align__(16) char smem[51968];
    f16*   Qs   = (f16*)smem;                 // [64][88]   ph1-2
    f16*   Ks   = (f16*)(smem + 11264);       // [192][88]  ph1-2
    float* Sc   = (float*)smem;               // [64][132]  ph2b-3a (alias Qs/Ks)
    f16*   P    = (f16*)smem;                 // [64][200]  ph3b-5  (alias Sc)
    f16*   Vt   = (f16*)(smem + 25600);       // [64][200]  ph4-5
    float* ksqs = (float*)(smem + 51200);     // [192]

    const int tid = threadIdx.x, w = tid >> 6, lane = tid & 63;
    const int lr = lane & 15, quad = lane >> 4;
    const int q0 = blockIdx.x * 64, bh = blockIdx.y;
    const int h = bh & 7, b = bh >> 3;
    const size_t tb = (size_t)bh * T_SEQ;
    const int ks0 = q0 - 128;

    // ---- phase 1: stage Q, K (+fused |k|^2) ----
    {
        const int row = tid >> 3, ch = tid & 7;
        f16x8 v = *(const f16x8*)(qh + (tb + q0 + row) * 64 + ch * 8);
        *(f16x8*)(Qs + row * 88 + ch * 8) = v;
    }
#pragma unroll
    for (int s = 0; s < 3; s++) {
        const int i = tid + 512 * s;
        const int row = i >> 3, ch = i & 7;
        const int kg = ks0 + row;
        f16x8 v = {};
        if (kg >= 0) v = *(const f16x8*)(kh + (tb + kg) * 64 + ch * 8);
        *(f16x8*)(Ks + row * 88 + ch * 8) = v;
        float ps = 0.f;
#pragma unroll
        for (int j = 0; j < 8; j++) { const float fv = (float)v[j]; ps += fv * fv; }
        ps += __shfl_xor(ps, 1);
        ps += __shfl_xor(ps, 2);
        ps += __shfl_xor(ps, 4);
        if (ch == 0) ksqs[row] = ps;
    }
    __syncthreads();   // B1

    // ---- phase 2: QK^T. wave = m-tile (w&3) x key-half (w>>2, 96 keys) ----
    const int mt  = w & 3;
    const int kh2 = w >> 2;
    f32x4 accQ[6];
#pragma unroll
    for (int jt = 0; jt < 6; jt++) accQ[jt] = (f32x4){0.f, 0.f, 0.f, 0.f};

    __builtin_amdgcn_s_setprio(1);
#pragma unroll
    for (int kp = 0; kp < 2; kp++) {
        const f16x8 af = *(const f16x8*)(Qs + (mt * 16 + lr) * 88 + kp * 32 + quad * 8);
#pragma unroll
        for (int jt = 0; jt < 6; jt++) {
            const f16x8 bf = *(const f16x8*)(Ks + (kh2 * 96 + jt * 16 + lr) * 88 + kp * 32 + quad * 8);
            accQ[jt] = __builtin_amdgcn_mfma_f32_16x16x32_f16(af, bf, accQ[jt], 0, 0, 0);
        }
    }
    __builtin_amdgcn_s_setprio(0);
    __syncthreads();   // B2: all Qs/Ks MFMA reads done -> Sc may alias them

    const float inv_s2 = __expf(-2.0f * logsig[h]);
#pragma unroll
    for (int jt = 0; jt < 6; jt++) {
        const int c  = kh2 * 96 + jt * 16 + lr;
        const float kq = ksqs[c];
        const int kg = ks0 + c;
#pragma unroll
        for (int r = 0; r < 4; r++) {
            const int dq = mt * 16 + quad * 4 + r;
            const unsigned wc = (unsigned)(c - dq - 1);
            if (wc < 128u) {
                Sc[dq * 132 + wc] = (kg >= 0) ? (accQ[jt][r] - 0.5f * kq) * inv_s2
                                              : -INFINITY;
            }
        }
    }

    // ---- T14: issue V^T global loads now; HBM latency hides under top-k ----
    f16x8 vpre[3];
#pragma unroll
    for (int s = 0; s < 3; s++) {
        const int i = tid + 512 * s;
        const int d = i / 24, ch = i % 24;
        const int t0v = ks0 + ch * 8;
        f16x8 vv = {};
        if (t0v >= 0) vv = *(const f16x8*)(vtg + ((size_t)bh * 64 + d) * T_SEQ + t0v);
        vpre[s] = vv;
    }
    __syncthreads();   // B3: Sc visible

    // ---- phase 3a: hoist ALL Sc reads to registers (keys + row max) ----
    const int wq8 = w * 8;
    unsigned u0[2][4], u1[2][4];
    float mx[2][4];
#pragma unroll
    for (int g = 0; g < 2; g++) {
#pragma unroll
        for (int qq = 0; qq < 4; qq++) {
            const int dq = wq8 + g * 4 + qq;
            const float s0 = Sc[dq * 132 + lane];
            const float s1 = Sc[dq * 132 + 64 + lane];
            const unsigned b0 = __float_as_uint(s0);
            const unsigned b1 = __float_as_uint(s1);
            u0[g][qq] = b0 ^ (unsigned)(((int)b0 >> 31) | 0x80000000);
            u1[g][qq] = b1 ^ (unsigned)(((int)b1 >> 31) | 0x80000000);
            mx[g][qq] = __uint_as_float(__builtin_amdgcn_readlane(__float_as_uint(s1), 63));
        }
    }
    __syncthreads();   // B4: all Sc reads done -> P/Vt may overwrite

    // ---- phase 4: write prefetched V^T (issues before the VALU search) ----
#pragma unroll
    for (int s = 0; s < 3; s++) {
        const int i = tid + 512 * s;
        const int d = i / 24, ch = i % 24;
        *(f16x8*)(Vt + d * 200 + ch * 8) = vpre[s];
    }

    // ---- phase 3b: exact top-96 ballot binary search (register-resident) ----
#pragma unroll 1
    for (int g = 0; g < 2; g++) {
        unsigned t[4];
#pragma unroll
        for (int qq = 0; qq < 4; qq++) t[qq] = 0u;
#pragma unroll
        for (int bit = 31; bit >= 0; bit--) {
#pragma unroll
            for (int qq = 0; qq < 4; qq++) {
                const unsigned c = t[qq] | (1u << bit);
                const int n = __popcll(__ballot(u0[g][qq] >= c)) +
                              __popcll(__ballot(u1[g][qq] >= c));
                if (n >= TOPK) t[qq] = c;
            }
        }
#pragma unroll
        for (int qq = 0; qq < 4; qq++) {
            const int dq = wq8 + g * 4 + qq;
            const float s0 = keyinv(u0[g][qq]);
            const float s1 = keyinv(u1[g][qq]);
            const float p0 = (u0[g][qq] >= t[qq]) ? __expf(s0 - mx[g][qq]) : 0.f;
            const float p1 = (u1[g][qq] >= t[qq]) ? __expf(s1 - mx[g][qq]) : 0.f;
            P[dq * 200 + dq + 1 + lane]  = (f16)p0;
            P[dq * 200 + dq + 65 + lane] = (f16)p1;
            P[dq * 200 + ((lane <= dq) ? lane : lane + 128)] = (f16)0.f;
        }
    }
    __syncthreads();   // B5: P, Vt ready

    // ---- phase 5: PV MFMA + ones-MFMA row sums ----
    const int nh = w >> 2;
    f32x4 accO[2];
#pragma unroll
    for (int nt = 0; nt < 2; nt++) accO[nt] = (f32x4){0.f, 0.f, 0.f, 0.f};
    f32x4 accS = (f32x4){0.f, 0.f, 0.f, 0.f};
    f16x8 onesf;
#pragma unroll
    for (int j = 0; j < 8; j++) onesf[j] = (f16)1.0f;

    __builtin_amdgcn_s_setprio(1);
#pragma unroll
    for (int ks = 0; ks < 6; ks++) {
        const f16x8 pf = *(const f16x8*)(P + (mt * 16 + lr) * 200 + ks * 32 + quad * 8);
#pragma unroll
        for (int nt = 0; nt < 2; nt++) {
            const f16x8 vf = *(const f16x8*)(Vt + (nh * 32 + nt * 16 + lr) * 200 + ks * 32 + quad * 8);
            accO[nt] = __builtin_amdgcn_mfma_f32_16x16x32_f16(pf, vf, accO[nt], 0, 0, 0);
        }
        accS = __builtin_amdgcn_mfma_f32_16x16x32_f16(pf, onesf, accS, 0, 0, 0);
    }
    __builtin_amdgcn_s_setprio(0);
    float inv[4];
#pragma unroll
    for (int r = 0; r < 4; r++) inv[r] = 1.0f / accS[r];

#pragma unroll
    for (int nt = 0; nt < 2; nt++) {
        const int d = nh * 32 + nt * 16 + lr;
#pragma unroll
        for (int r = 0; r < 4; r++) {
            const int q = q0 + mt * 16 + quad * 4 + r;
            abh[((size_t)(b * T_SEQ + q)) * 512 + h * 64 + d] = (f16)(accO[nt][r] * inv[r]);
        }
    }
}

// ---------------------------------------------------------------------------
extern "C" void kernel_launch(void* const* d_in, const int* in_sizes, int n_in,
                              void* d_out, int out_size, void* d_ws, size_t ws_size,
                              hipStream_t stream)
{
    const float* x      = (const float*)d_in[0];
    const float* Wq     = (const float*)d_in[1];
    const float* bq     = (const float*)d_in[2];
    const float* Wk     = (const float*)d_in[3];
    const float* bk     = (const float*)d_in[4];
    const float* Wv     = (const float*)d_in[5];
    const float* bv     = (const float*)d_in[6];
    const float* Wo     = (const float*)d_in[7];
    const float* bo     = (const float*)d_in[8];
    const float* logsig = (const float*)d_in[9];

    f16* xh    = (f16*)d_ws;              // 4,194,304
    f16* wqkvh = xh + 4194304;            // 786,432
    f16* woh   = wqkvh + 786432;          // 262,144
    f16* qh    = woh + 262144;            // 4,194,304  [B,H,T,64]
    f16* kh    = qh + 4194304;            // 4,194,304  [B,H,T,64]
    f16* vtg   = kh + 4194304;            // 4,194,304  [B,H,64,T]
    f16* abh   = xh;                      // alias: x dead after QKV GEMM

    convert_all<<<5120, 256, 0, stream>>>(x, Wq, Wk, Wv, Wo, xh, wqkvh, woh);

    gemm_qkv<<<dim3(64, 12), 256, 0, stream>>>(xh, wqkvh, bq, bk, bv, qh, kh, vtg);

    attn_v6<<<dim3(T_SEQ / 64, BATCH * NHEADS), 512, 0, stream>>>(
        qh, kh, vtg, logsig, abh);

    gemm_o<<<dim3(64, 8), 256, 0, stream>>>(abh, woh, bo, (float*)d_out);
}

// Round 5
// 179.619 us; speedup vs baseline: 3.8691x; 1.0702x over previous
//
#include <hip/hip_runtime.h>
#include <math.h>

#define T_SEQ   2048
#define EDIM    512
#define NHEADS  8
#define DHEAD   64
#define BATCH   4
#define WIN     128
#define TOPK    96

typedef _Float16 f16;
typedef f16 f16x2 __attribute__((ext_vector_type(2)));
typedef f16 f16x4 __attribute__((ext_vector_type(4)));
typedef f16 f16x8 __attribute__((ext_vector_type(8)));
typedef float f32x4 __attribute__((ext_vector_type(4)));

#define GLD_LDS(gp, lp) \
    __builtin_amdgcn_global_load_lds((const __attribute__((address_space(1))) void*)(gp), \
                                     (__attribute__((address_space(3))) void*)(lp), 16, 0, 0)

// ---------------------------------------------------------------------------
// fp32 -> f16 conversion of x, Wq, Wk, Wv, Wo. 4 elems/thread.
// ---------------------------------------------------------------------------
__global__ __launch_bounds__(256) void convert_all(
    const float* __restrict__ x,  const float* __restrict__ wq,
    const float* __restrict__ wk, const float* __restrict__ wv,
    const float* __restrict__ wo,
    f16* __restrict__ xh, f16* __restrict__ wqkvh, f16* __restrict__ woh)
{
    long i = ((long)blockIdx.x * 256 + threadIdx.x) * 4;
    const float* src; f16* dst; long off;
    if      (i < 4194304L) { src = x;  dst = xh;             off = i;            }
    else if (i < 4456448L) { src = wq; dst = wqkvh;          off = i - 4194304L; }
    else if (i < 4718592L) { src = wk; dst = wqkvh + 262144; off = i - 4456448L; }
    else if (i < 4980736L) { src = wv; dst = wqkvh + 524288; off = i - 4718592L; }
    else                   { src = wo; dst = woh;            off = i - 4980736L; }
    float4 v = *(const float4*)(src + off);
    f16x4 h; h.x = (f16)v.x; h.y = (f16)v.y; h.z = (f16)v.z; h.w = (f16)v.w;
    *(f16x4*)(dst + off) = h;
}

// ---------------------------------------------------------------------------
// QKV f16 MFMA GEMM (m97-pattern): 128x128 tile, BK=64, 256 threads.
// ---------------------------------------------------------------------------
__global__ __launch_bounds__(256) void gemm_qkv(
    const f16* __restrict__ A, const f16* __restrict__ W,
    const float* __restrict__ b0, const float* __restrict__ b1,
    const float* __restrict__ b2,
    f16* __restrict__ cq, f16* __restrict__ ck, f16* __restrict__ cv)
{
    __shared__ f16 SH[16384];
    f16* Ash = SH;
    f16* Bsh = SH + 8192;

    const int tid  = threadIdx.x;
    const int w    = tid >> 6;
    const int lane = tid & 63;
    const int m0   = blockIdx.x * 128;
    const int n0   = blockIdx.y * 128;
    const int K    = 512;
    const int lr   = lane & 15;
    const int lk8  = (lane >> 4) * 8;

    f32x4 acc[4][4];
#pragma unroll
    for (int i = 0; i < 4; i++)
#pragma unroll
        for (int j = 0; j < 4; j++) acc[i][j] = (f32x4){0.f, 0.f, 0.f, 0.f};

    const int wmi = (w & 1) * 4;
    const int wni = (w >> 1) * 4;

    for (int k0 = 0; k0 < K; k0 += 64) {
#pragma unroll
        for (int cc = 0; cc < 4; cc++) {
            const int c  = w * 4 + cc;
            const int ms = c & 7, kp = c >> 3;
            const int kcol = k0 + kp * 32 + lk8;
            GLD_LDS(A + (size_t)(m0 + ms * 16 + lr) * K + kcol, Ash + c * 512);
            GLD_LDS(W + (size_t)(n0 + ms * 16 + lr) * K + kcol, Bsh + c * 512);
        }
        __syncthreads();

#pragma unroll
        for (int kp = 0; kp < 2; kp++) {
            f16x8 af[4], bf[4];
#pragma unroll
            for (int i = 0; i < 4; i++)
                af[i] = *(const f16x8*)(Ash + (kp * 8 + wmi + i) * 512 + lane * 8);
#pragma unroll
            for (int j = 0; j < 4; j++)
                bf[j] = *(const f16x8*)(Bsh + (kp * 8 + wni + j) * 512 + lane * 8);
#pragma unroll
            for (int i = 0; i < 4; i++)
#pragma unroll
                for (int j = 0; j < 4; j++)
                    acc[i][j] = __builtin_amdgcn_mfma_f32_16x16x32_f16(af[i], bf[j], acc[i][j], 0, 0, 0);
        }
        __syncthreads();
    }

    const int quad = lane >> 4;
    const int mat  = n0 >> 9;
    const float* bias = (mat == 0) ? b0 : ((mat == 1) ? b1 : b2);
    const int bb  = m0 >> 11;
    const int t0  = m0 & (T_SEQ - 1);
    const int hh0 = (n0 & 511) >> 6;

    if (mat < 2) {
#pragma unroll
        for (int i = 0; i < 4; i++) {
#pragma unroll
            for (int j = 0; j < 4; j++) {
                const int nl = (w >> 1) * 64 + j * 16 + lr;
                const float bvv = bias[(n0 & 511) + nl];
#pragma unroll
                for (int r = 0; r < 4; r++) {
                    const int ml = (w & 1) * 64 + i * 16 + quad * 4 + r;
                    SH[ml * 128 + (nl ^ (((ml >> 2) & 7) << 4))] = (f16)(acc[i][j][r] + bvv);
                }
            }
        }
        __syncthreads();
        f16* dst = (mat == 0) ? cq : ck;
#pragma unroll
        for (int s = 0; s < 8; s++) {
            const int c   = tid + 256 * s;
            const int row = c >> 4;
            const int nt  = (c & 15) * 8;
            const f16x8 vv = *(const f16x8*)&SH[row * 128 + (nt ^ (((row >> 2) & 7) << 4))];
            const int hh = hh0 + (nt >> 6);
            const int dd = nt & 63;
            *(f16x8*)(dst + ((size_t)((bb * NHEADS + hh) * T_SEQ) + t0 + row) * 64 + dd) = vv;
        }
    } else {
#pragma unroll
        for (int i = 0; i < 4; i++) {
#pragma unroll
            for (int j = 0; j < 4; j++) {
                const int nl = (w >> 1) * 64 + j * 16 + lr;
                const float bvv = bias[(n0 & 511) + nl];
                const int mlb = (w & 1) * 64 + i * 16 + quad * 4;
                f16x4 pk;
#pragma unroll
                for (int r = 0; r < 4; r++) pk[r] = (f16)(acc[i][j][r] + bvv);
                *(f16x4*)&SH[nl * 128 + ((mlb + 8 * (nl & 15)) & 127)] = pk;
            }
        }
        __syncthreads();
#pragma unroll
        for (int s = 0; s < 8; s++) {
            const int c    = tid + 256 * s;
            const int nrow = c >> 4;
            const int cht  = c & 15;
            const int chl  = (cht + (nrow & 15)) & 15;
            const f16x8 vv = *(const f16x8*)&SH[nrow * 128 + chl * 8];
            const int hh = hh0 + (nrow >> 6);
            const int dd = nrow & 63;
            *(f16x8*)(cv + ((size_t)((bb * NHEADS + hh) * 64 + dd)) * T_SEQ + t0 + cht * 8) = vv;
        }
    }
}

// ---------------------------------------------------------------------------
// Output-projection GEMM: 128x64 tile, BK=64, 256 threads -> 512 blocks.
// LDS-transposed epilogue (stride-68 fp32 tile), coalesced f32x4 stores.
// ---------------------------------------------------------------------------
__global__ __launch_bounds__(256) void gemm_o(
    const f16* __restrict__ A, const f16* __restrict__ W,
    const float* __restrict__ bias, float* __restrict__ C)
{
    __shared__ __align__(16) char SMO[34816];
    f16*   Ash = (f16*)SMO;
    f16*   Bsh = (f16*)(SMO + 16384);
    float* SC  = (float*)SMO;

    const int tid  = threadIdx.x;
    const int w    = tid >> 6;
    const int lane = tid & 63;
    const int m0   = blockIdx.x * 128;
    const int n0   = blockIdx.y * 64;
    const int lr   = lane & 15;
    const int lk8  = (lane >> 4) * 8;

    f32x4 acc[4][2];
#pragma unroll
    for (int i = 0; i < 4; i++)
#pragma unroll
        for (int j = 0; j < 2; j++) acc[i][j] = (f32x4){0.f, 0.f, 0.f, 0.f};

    for (int k0 = 0; k0 < 512; k0 += 64) {
#pragma unroll
        for (int cc = 0; cc < 4; cc++) {
            const int c  = w * 4 + cc;
            const int ms = c & 7, kp = c >> 3;
            GLD_LDS(A + (size_t)(m0 + ms * 16 + lr) * 512 + k0 + kp * 32 + lk8, Ash + c * 512);
        }
#pragma unroll
        for (int cc = 0; cc < 2; cc++) {
            const int c  = w * 2 + cc;
            const int ns = c & 3, kp = c >> 2;
            GLD_LDS(W + (size_t)(n0 + ns * 16 + lr) * 512 + k0 + kp * 32 + lk8, Bsh + c * 512);
        }
        __syncthreads();

#pragma unroll
        for (int kp = 0; kp < 2; kp++) {
            f16x8 af[4], bf[2];
#pragma unroll
            for (int i = 0; i < 4; i++)
                af[i] = *(const f16x8*)(Ash + (kp * 8 + (w & 1) * 4 + i) * 512 + lane * 8);
#pragma unroll
            for (int j = 0; j < 2; j++)
                bf[j] = *(const f16x8*)(Bsh + (kp * 4 + (w >> 1) * 2 + j) * 512 + lane * 8);
#pragma unroll
            for (int i = 0; i < 4; i++)
#pragma unroll
                for (int j = 0; j < 2; j++)
                    acc[i][j] = __builtin_amdgcn_mfma_f32_16x16x32_f16(af[i], bf[j], acc[i][j], 0, 0, 0);
        }
        __syncthreads();
    }

    const int quad = lane >> 4;
#pragma unroll
    for (int i = 0; i < 4; i++) {
#pragma unroll
        for (int j = 0; j < 2; j++) {
            const int n  = (w >> 1) * 32 + j * 16 + lr;
            const float bv = bias[n0 + n];
#pragma unroll
            for (int r = 0; r < 4; r++) {
                const int m = (w & 1) * 64 + i * 16 + quad * 4 + r;
                SC[m * 68 + n] = acc[i][j][r] + bv;
            }
        }
    }
    __syncthreads();
#pragma unroll
    for (int s = 0; s < 8; s++) {
        const int c   = tid + 256 * s;
        const int row = c >> 4;
        const int nt  = (c & 15) * 4;
        const f32x4 vv = *(const f32x4*)&SC[row * 68 + nt];
        *(f32x4*)&C[(size_t)(m0 + row) * 512 + n0 + nt] = vv;
    }
}

// ---------------------------------------------------------------------------
// Attention v7 = v6 LDS layout (50.8KB -> 3 blocks/CU) with the register
// pressure fixed:
//   - __launch_bounds__(512, 4): round-4's (512,6) forced VGPR 40 -> ~48MB
//     scratch spill per dispatch (WRITE_SIZE 57MB vs 8MB output). Budget 128
//     lets the allocator sit at its natural ~55-60.
//   - mx (row max) hoist REMOVED: the diagonal score ~= 0 and softmax is
//     exactly shift-invariant here (normalizer is the ones-MFMA row sum of
//     the same p values) -> p = exp(s) directly. -8 VGPR, -8 readlane.
// ---------------------------------------------------------------------------
__device__ __forceinline__ float keyinv(unsigned u)
{
    unsigned b = u ^ ((unsigned)((int)(~u) >> 31) | 0x80000000u);
    return __uint_as_float(b);
}

__global__ __launch_bounds__(512, 4) void attn_v7(
    const f16* __restrict__ qh, const f16* __restrict__ kh,
    const f16* __restrict__ vtg, const float* __restrict__ logsig,
    f16* __restrict__ abh)
{
    __shared__ __align__(16) char smem[51968];
    f16*   Qs   = (f16*)smem;                 // [64][88]   ph1-2
    f16*   Ks   = (f16*)(smem + 11264);       // [192][88]  ph1-2
    float* Sc   = (float*)smem;               // [64][132]  ph2b-3a (alias Qs/Ks)
    f16*   P    = (f16*)smem;                 // [64][200]  ph3b-5  (alias Sc)
    f16*   Vt   = (f16*)(smem + 25600);       // [64][200]  ph4-5
    float* ksqs = (float*)(smem + 51200);     // [192]

    const int tid = threadIdx.x, w = tid >> 6, lane = tid & 63;
    const int lr = lane & 15, quad = lane >> 4;
    const int q0 = blockIdx.x * 64, bh = blockIdx.y;
    const int h = bh & 7, b = bh >> 3;
    const size_t tb = (size_t)bh * T_SEQ;
    const int ks0 = q0 - 128;

    // ---- phase 1: stage Q, K (+fused |k|^2) ----
    {
        const int row = tid >> 3, ch = tid & 7;
        f16x8 v = *(const f16x8*)(qh + (tb + q0 + row) * 64 + ch * 8);
        *(f16x8*)(Qs + row * 88 + ch * 8) = v;
    }
#pragma unroll
    for (int s = 0; s < 3; s++) {
        const int i = tid + 512 * s;
        const int row = i >> 3, ch = i & 7;
        const int kg = ks0 + row;
        f16x8 v = {};
        if (kg >= 0) v = *(const f16x8*)(kh + (tb + kg) * 64 + ch * 8);
        *(f16x8*)(Ks + row * 88 + ch * 8) = v;
        float ps = 0.f;
#pragma unroll
        for (int j = 0; j < 8; j++) { const float fv = (float)v[j]; ps += fv * fv; }
        ps += __shfl_xor(ps, 1);
        ps += __shfl_xor(ps, 2);
        ps += __shfl_xor(ps, 4);
        if (ch == 0) ksqs[row] = ps;
    }
    __syncthreads();   // B1

    // ---- phase 2: QK^T. wave = m-tile (w&3) x key-half (w>>2, 96 keys) ----
    const int mt  = w & 3;
    const int kh2 = w >> 2;
    f32x4 accQ[6];
#pragma unroll
    for (int jt = 0; jt < 6; jt++) accQ[jt] = (f32x4){0.f, 0.f, 0.f, 0.f};

    __builtin_amdgcn_s_setprio(1);
#pragma unroll
    for (int kp = 0; kp < 2; kp++) {
        const f16x8 af = *(const f16x8*)(Qs + (mt * 16 + lr) * 88 + kp * 32 + quad * 8);
#pragma unroll
        for (int jt = 0; jt < 6; jt++) {
            const f16x8 bf = *(const f16x8*)(Ks + (kh2 * 96 + jt * 16 + lr) * 88 + kp * 32 + quad * 8);
            accQ[jt] = __builtin_amdgcn_mfma_f32_16x16x32_f16(af, bf, accQ[jt], 0, 0, 0);
        }
    }
    __builtin_amdgcn_s_setprio(0);
    __syncthreads();   // B2: all Qs/Ks MFMA reads done -> Sc may alias them

    const float inv_s2 = __expf(-2.0f * logsig[h]);
#pragma unroll
    for (int jt = 0; jt < 6; jt++) {
        const int c  = kh2 * 96 + jt * 16 + lr;
        const float kq = ksqs[c];
        const int kg = ks0 + c;
#pragma unroll
        for (int r = 0; r < 4; r++) {
            const int dq = mt * 16 + quad * 4 + r;
            const unsigned wc = (unsigned)(c - dq - 1);
            if (wc < 128u) {
                Sc[dq * 132 + wc] = (kg >= 0) ? (accQ[jt][r] - 0.5f * kq) * inv_s2
                                              : -INFINITY;
            }
        }
    }

    // ---- T14: issue V^T global loads now; HBM latency hides under top-k ----
    f16x8 vpre[3];
#pragma unroll
    for (int s = 0; s < 3; s++) {
        const int i = tid + 512 * s;
        const int d = i / 24, ch = i % 24;
        const int t0v = ks0 + ch * 8;
        f16x8 vv = {};
        if (t0v >= 0) vv = *(const f16x8*)(vtg + ((size_t)bh * 64 + d) * T_SEQ + t0v);
        vpre[s] = vv;
    }
    __syncthreads();   // B3: Sc visible

    // ---- phase 3a: hoist ALL Sc reads to registers ----
    const int wq8 = w * 8;
    unsigned u0[2][4], u1[2][4];
#pragma unroll
    for (int g = 0; g < 2; g++) {
#pragma unroll
        for (int qq = 0; qq < 4; qq++) {
            const int dq = wq8 + g * 4 + qq;
            const float s0 = Sc[dq * 132 + lane];
            const float s1 = Sc[dq * 132 + 64 + lane];
            const unsigned b0 = __float_as_uint(s0);
            const unsigned b1 = __float_as_uint(s1);
            u0[g][qq] = b0 ^ (unsigned)(((int)b0 >> 31) | 0x80000000);
            u1[g][qq] = b1 ^ (unsigned)(((int)b1 >> 31) | 0x80000000);
        }
    }
    __syncthreads();   // B4: all Sc reads done -> P/Vt may overwrite

    // ---- phase 4: write prefetched V^T (issues before the VALU search) ----
#pragma unroll
    for (int s = 0; s < 3; s++) {
        const int i = tid + 512 * s;
        const int d = i / 24, ch = i % 24;
        *(f16x8*)(Vt + d * 200 + ch * 8) = vpre[s];
    }

    // ---- phase 3b: exact top-96 ballot binary search (register-resident).
    //      p = exp(s) (no max shift: diagonal ~0, normalizer cancels scale) ----
#pragma unroll 1
    for (int g = 0; g < 2; g++) {
        unsigned t[4];
#pragma unroll
        for (int qq = 0; qq < 4; qq++) t[qq] = 0u;
#pragma unroll
        for (int bit = 31; bit >= 0; bit--) {
#pragma unroll
            for (int qq = 0; qq < 4; qq++) {
                const unsigned c = t[qq] | (1u << bit);
                const int n = __popcll(__ballot(u0[g][qq] >= c)) +
                              __popcll(__ballot(u1[g][qq] >= c));
                if (n >= TOPK) t[qq] = c;
            }
        }
#pragma unroll
        for (int qq = 0; qq < 4; qq++) {
            const int dq = wq8 + g * 4 + qq;
            const float p0 = (u0[g][qq] >= t[qq]) ? __expf(keyinv(u0[g][qq])) : 0.f;
            const float p1 = (u1[g][qq] >= t[qq]) ? __expf(keyinv(u1[g][qq])) : 0.f;
            P[dq * 200 + dq + 1 + lane]  = (f16)p0;
            P[dq * 200 + dq + 65 + lane] = (f16)p1;
            P[dq * 200 + ((lane <= dq) ? lane : lane + 128)] = (f16)0.f;
        }
    }
    __syncthreads();   // B5: P, Vt ready

    // ---- phase 5: PV MFMA + ones-MFMA row sums ----
    const int nh = w >> 2;
    f32x4 accO[2];
#pragma unroll
    for (int nt = 0; nt < 2; nt++) accO[nt] = (f32x4){0.f, 0.f, 0.f, 0.f};
    f32x4 accS = (f32x4){0.f, 0.f, 0.f, 0.f};
    f16x8 onesf;
#pragma unroll
    for (int j = 0; j < 8; j++) onesf[j] = (f16)1.0f;

    __builtin_amdgcn_s_setprio(1);
#pragma unroll
    for (int ks = 0; ks < 6; ks++) {
        const f16x8 pf = *(const f16x8*)(P + (mt * 16 + lr) * 200 + ks * 32 + quad * 8);
#pragma unroll
        for (int nt = 0; nt < 2; nt++) {
            const f16x8 vf = *(const f16x8*)(Vt + (nh * 32 + nt * 16 + lr) * 200 + ks * 32 + quad * 8);
            accO[nt] = __builtin_amdgcn_mfma_f32_16x16x32_f16(pf, vf, accO[nt], 0, 0, 0);
        }
        accS = __builtin_amdgcn_mfma_f32_16x16x32_f16(pf, onesf, accS, 0, 0, 0);
    }
    __builtin_amdgcn_s_setprio(0);
    float inv[4];
#pragma unroll
    for (int r = 0; r < 4; r++) inv[r] = 1.0f / accS[r];

#pragma unroll
    for (int nt = 0; nt < 2; nt++) {
        const int d = nh * 32 + nt * 16 + lr;
#pragma unroll
        for (int r = 0; r < 4; r++) {
            const int q = q0 + mt * 16 + quad * 4 + r;
            abh[((size_t)(b * T_SEQ + q)) * 512 + h * 64 + d] = (f16)(accO[nt][r] * inv[r]);
        }
    }
}

// ---------------------------------------------------------------------------
extern "C" void kernel_launch(void* const* d_in, const int* in_sizes, int n_in,
                              void* d_out, int out_size, void* d_ws, size_t ws_size,
                              hipStream_t stream)
{
    const float* x      = (const float*)d_in[0];
    const float* Wq     = (const float*)d_in[1];
    const float* bq     = (const float*)d_in[2];
    const float* Wk     = (const float*)d_in[3];
    const float* bk     = (const float*)d_in[4];
    const float* Wv     = (const float*)d_in[5];
    const float* bv     = (const float*)d_in[6];
    const float* Wo     = (const float*)d_in[7];
    const float* bo     = (const float*)d_in[8];
    const float* logsig = (const float*)d_in[9];

    f16* xh    = (f16*)d_ws;              // 4,194,304
    f16* wqkvh = xh + 4194304;            // 786,432
    f16* woh   = wqkvh + 786432;          // 262,144
    f16* qh    = woh + 262144;            // 4,194,304  [B,H,T,64]
    f16* kh    = qh + 4194304;            // 4,194,304  [B,H,T,64]
    f16* vtg   = kh + 4194304;            // 4,194,304  [B,H,64,T]
    f16* abh   = xh;                      // alias: x dead after QKV GEMM

    convert_all<<<5120, 256, 0, stream>>>(x, Wq, Wk, Wv, Wo, xh, wqkvh, woh);

    gemm_qkv<<<dim3(64, 12), 256, 0, stream>>>(xh, wqkvh, bq, bk, bv, qh, kh, vtg);

    attn_v7<<<dim3(T_SEQ / 64, BATCH * NHEADS), 512, 0, stream>>>(
        qh, kh, vtg, logsig, abh);

    gemm_o<<<dim3(64, 8), 256, 0, stream>>>(abh, woh, bo, (float*)d_out);
}

// Round 6
// 169.938 us; speedup vs baseline: 4.0895x; 1.0570x over previous
//
#include <hip/hip_runtime.h>
#include <math.h>

#define T_SEQ   2048
#define EDIM    512
#define NHEADS  8
#define DHEAD   64
#define BATCH   4
#define WIN     128
#define TOPK    96

typedef _Float16 f16;
typedef f16 f16x2 __attribute__((ext_vector_type(2)));
typedef f16 f16x4 __attribute__((ext_vector_type(4)));
typedef f16 f16x8 __attribute__((ext_vector_type(8)));
typedef float f32x4 __attribute__((ext_vector_type(4)));

#define GLD_LDS(gp, lp) \
    __builtin_amdgcn_global_load_lds((const __attribute__((address_space(1))) void*)(gp), \
                                     (__attribute__((address_space(3))) void*)(lp), 16, 0, 0)

// ---------------------------------------------------------------------------
// fp32 -> f16 conversion of x, Wq, Wk, Wv, Wo. 4 elems/thread.
// ---------------------------------------------------------------------------
__global__ __launch_bounds__(256) void convert_all(
    const float* __restrict__ x,  const float* __restrict__ wq,
    const float* __restrict__ wk, const float* __restrict__ wv,
    const float* __restrict__ wo,
    f16* __restrict__ xh, f16* __restrict__ wqkvh, f16* __restrict__ woh)
{
    long i = ((long)blockIdx.x * 256 + threadIdx.x) * 4;
    const float* src; f16* dst; long off;
    if      (i < 4194304L) { src = x;  dst = xh;             off = i;            }
    else if (i < 4456448L) { src = wq; dst = wqkvh;          off = i - 4194304L; }
    else if (i < 4718592L) { src = wk; dst = wqkvh + 262144; off = i - 4456448L; }
    else if (i < 4980736L) { src = wv; dst = wqkvh + 524288; off = i - 4718592L; }
    else                   { src = wo; dst = woh;            off = i - 4980736L; }
    float4 v = *(const float4*)(src + off);
    f16x4 h; h.x = (f16)v.x; h.y = (f16)v.y; h.z = (f16)v.z; h.w = (f16)v.w;
    *(f16x4*)(dst + off) = h;
}

// ---------------------------------------------------------------------------
// QKV f16 MFMA GEMM (m97-pattern): 128x128 tile, BK=64, 256 threads.
// ---------------------------------------------------------------------------
__global__ __launch_bounds__(256) void gemm_qkv(
    const f16* __restrict__ A, const f16* __restrict__ W,
    const float* __restrict__ b0, const float* __restrict__ b1,
    const float* __restrict__ b2,
    f16* __restrict__ cq, f16* __restrict__ ck, f16* __restrict__ cv)
{
    __shared__ f16 SH[16384];
    f16* Ash = SH;
    f16* Bsh = SH + 8192;

    const int tid  = threadIdx.x;
    const int w    = tid >> 6;
    const int lane = tid & 63;
    const int m0   = blockIdx.x * 128;
    const int n0   = blockIdx.y * 128;
    const int K    = 512;
    const int lr   = lane & 15;
    const int lk8  = (lane >> 4) * 8;

    f32x4 acc[4][4];
#pragma unroll
    for (int i = 0; i < 4; i++)
#pragma unroll
        for (int j = 0; j < 4; j++) acc[i][j] = (f32x4){0.f, 0.f, 0.f, 0.f};

    const int wmi = (w & 1) * 4;
    const int wni = (w >> 1) * 4;

    for (int k0 = 0; k0 < K; k0 += 64) {
#pragma unroll
        for (int cc = 0; cc < 4; cc++) {
            const int c  = w * 4 + cc;
            const int ms = c & 7, kp = c >> 3;
            const int kcol = k0 + kp * 32 + lk8;
            GLD_LDS(A + (size_t)(m0 + ms * 16 + lr) * K + kcol, Ash + c * 512);
            GLD_LDS(W + (size_t)(n0 + ms * 16 + lr) * K + kcol, Bsh + c * 512);
        }
        __syncthreads();

#pragma unroll
        for (int kp = 0; kp < 2; kp++) {
            f16x8 af[4], bf[4];
#pragma unroll
            for (int i = 0; i < 4; i++)
                af[i] = *(const f16x8*)(Ash + (kp * 8 + wmi + i) * 512 + lane * 8);
#pragma unroll
            for (int j = 0; j < 4; j++)
                bf[j] = *(const f16x8*)(Bsh + (kp * 8 + wni + j) * 512 + lane * 8);
#pragma unroll
            for (int i = 0; i < 4; i++)
#pragma unroll
                for (int j = 0; j < 4; j++)
                    acc[i][j] = __builtin_amdgcn_mfma_f32_16x16x32_f16(af[i], bf[j], acc[i][j], 0, 0, 0);
        }
        __syncthreads();
    }

    const int quad = lane >> 4;
    const int mat  = n0 >> 9;
    const float* bias = (mat == 0) ? b0 : ((mat == 1) ? b1 : b2);
    const int bb  = m0 >> 11;
    const int t0  = m0 & (T_SEQ - 1);
    const int hh0 = (n0 & 511) >> 6;

    if (mat < 2) {
#pragma unroll
        for (int i = 0; i < 4; i++) {
#pragma unroll
            for (int j = 0; j < 4; j++) {
                const int nl = (w >> 1) * 64 + j * 16 + lr;
                const float bvv = bias[(n0 & 511) + nl];
#pragma unroll
                for (int r = 0; r < 4; r++) {
                    const int ml = (w & 1) * 64 + i * 16 + quad * 4 + r;
                    SH[ml * 128 + (nl ^ (((ml >> 2) & 7) << 4))] = (f16)(acc[i][j][r] + bvv);
                }
            }
        }
        __syncthreads();
        f16* dst = (mat == 0) ? cq : ck;
#pragma unroll
        for (int s = 0; s < 8; s++) {
            const int c   = tid + 256 * s;
            const int row = c >> 4;
            const int nt  = (c & 15) * 8;
            const f16x8 vv = *(const f16x8*)&SH[row * 128 + (nt ^ (((row >> 2) & 7) << 4))];
            const int hh = hh0 + (nt >> 6);
            const int dd = nt & 63;
            *(f16x8*)(dst + ((size_t)((bb * NHEADS + hh) * T_SEQ) + t0 + row) * 64 + dd) = vv;
        }
    } else {
#pragma unroll
        for (int i = 0; i < 4; i++) {
#pragma unroll
            for (int j = 0; j < 4; j++) {
                const int nl = (w >> 1) * 64 + j * 16 + lr;
                const float bvv = bias[(n0 & 511) + nl];
                const int mlb = (w & 1) * 64 + i * 16 + quad * 4;
                f16x4 pk;
#pragma unroll
                for (int r = 0; r < 4; r++) pk[r] = (f16)(acc[i][j][r] + bvv);
                *(f16x4*)&SH[nl * 128 + ((mlb + 8 * (nl & 15)) & 127)] = pk;
            }
        }
        __syncthreads();
#pragma unroll
        for (int s = 0; s < 8; s++) {
            const int c    = tid + 256 * s;
            const int nrow = c >> 4;
            const int cht  = c & 15;
            const int chl  = (cht + (nrow & 15)) & 15;
            const f16x8 vv = *(const f16x8*)&SH[nrow * 128 + chl * 8];
            const int hh = hh0 + (nrow >> 6);
            const int dd = nrow & 63;
            *(f16x8*)(cv + ((size_t)((bb * NHEADS + hh) * 64 + dd)) * T_SEQ + t0 + cht * 8) = vv;
        }
    }
}

// ---------------------------------------------------------------------------
// Output-projection GEMM: 128x64 tile, BK=64, 256 threads -> 512 blocks.
// ---------------------------------------------------------------------------
__global__ __launch_bounds__(256) void gemm_o(
    const f16* __restrict__ A, const f16* __restrict__ W,
    const float* __restrict__ bias, float* __restrict__ C)
{
    __shared__ __align__(16) char SMO[34816];
    f16*   Ash = (f16*)SMO;
    f16*   Bsh = (f16*)(SMO + 16384);
    float* SC  = (float*)SMO;

    const int tid  = threadIdx.x;
    const int w    = tid >> 6;
    const int lane = tid & 63;
    const int m0   = blockIdx.x * 128;
    const int n0   = blockIdx.y * 64;
    const int lr   = lane & 15;
    const int lk8  = (lane >> 4) * 8;

    f32x4 acc[4][2];
#pragma unroll
    for (int i = 0; i < 4; i++)
#pragma unroll
        for (int j = 0; j < 2; j++) acc[i][j] = (f32x4){0.f, 0.f, 0.f, 0.f};

    for (int k0 = 0; k0 < 512; k0 += 64) {
#pragma unroll
        for (int cc = 0; cc < 4; cc++) {
            const int c  = w * 4 + cc;
            const int ms = c & 7, kp = c >> 3;
            GLD_LDS(A + (size_t)(m0 + ms * 16 + lr) * 512 + k0 + kp * 32 + lk8, Ash + c * 512);
        }
#pragma unroll
        for (int cc = 0; cc < 2; cc++) {
            const int c  = w * 2 + cc;
            const int ns = c & 3, kp = c >> 2;
            GLD_LDS(W + (size_t)(n0 + ns * 16 + lr) * 512 + k0 + kp * 32 + lk8, Bsh + c * 512);
        }
        __syncthreads();

#pragma unroll
        for (int kp = 0; kp < 2; kp++) {
            f16x8 af[4], bf[2];
#pragma unroll
            for (int i = 0; i < 4; i++)
                af[i] = *(const f16x8*)(Ash + (kp * 8 + (w & 1) * 4 + i) * 512 + lane * 8);
#pragma unroll
            for (int j = 0; j < 2; j++)
                bf[j] = *(const f16x8*)(Bsh + (kp * 4 + (w >> 1) * 2 + j) * 512 + lane * 8);
#pragma unroll
            for (int i = 0; i < 4; i++)
#pragma unroll
                for (int j = 0; j < 2; j++)
                    acc[i][j] = __builtin_amdgcn_mfma_f32_16x16x32_f16(af[i], bf[j], acc[i][j], 0, 0, 0);
        }
        __syncthreads();
    }

    const int quad = lane >> 4;
#pragma unroll
    for (int i = 0; i < 4; i++) {
#pragma unroll
        for (int j = 0; j < 2; j++) {
            const int n  = (w >> 1) * 32 + j * 16 + lr;
            const float bv = bias[n0 + n];
#pragma unroll
            for (int r = 0; r < 4; r++) {
                const int m = (w & 1) * 64 + i * 16 + quad * 4 + r;
                SC[m * 68 + n] = acc[i][j][r] + bv;
            }
        }
    }
    __syncthreads();
#pragma unroll
    for (int s = 0; s < 8; s++) {
        const int c   = tid + 256 * s;
        const int row = c >> 4;
        const int nt  = (c & 15) * 4;
        const f32x4 vv = *(const f32x4*)&SC[row * 68 + nt];
        *(f32x4*)&C[(size_t)(m0 + row) * 512 + n0 + nt] = vv;
    }
}

// ---------------------------------------------------------------------------
// Attention v8 = v7 with the rule-#20 scratch bug fixed: the top-k g-loop is
// FULLY UNROLLED so u0/u1 indices are compile-time constants -> registers
// (v6/v7 had "#pragma unroll 1" -> runtime-indexed arrays -> ~32MB scratch
// traffic per dispatch, VGPR demoted to 40, WRITE_SIZE 40MB vs 8MB output).
// LDS 50.8KB; __launch_bounds__(512,6) caps VGPR at ~85 (natural ~60 fits)
// and pins 3 blocks/CU (24 waves, 75% occupancy).
// ---------------------------------------------------------------------------
__device__ __forceinline__ float keyinv(unsigned u)
{
    unsigned b = u ^ ((unsigned)((int)(~u) >> 31) | 0x80000000u);
    return __uint_as_float(b);
}

__global__ __launch_bounds__(512, 6) void attn_v8(
    const f16* __restrict__ qh, const f16* __restrict__ kh,
    const f16* __restrict__ vtg, const float* __restrict__ logsig,
    f16* __restrict__ abh)
{
    __shared__ __align__(16) char smem[51968];
    f16*   Qs   = (f16*)smem;                 // [64][88]   ph1-2
    f16*   Ks   = (f16*)(smem + 11264);       // [192][88]  ph1-2
    float* Sc   = (float*)smem;               // [64][132]  ph2b-3a (alias Qs/Ks)
    f16*   P    = (f16*)smem;                 // [64][200]  ph3b-5  (alias Sc)
    f16*   Vt   = (f16*)(smem + 25600);       // [64][200]  ph4-5
    float* ksqs = (float*)(smem + 51200);     // [192]

    const int tid = threadIdx.x, w = tid >> 6, lane = tid & 63;
    const int lr = lane & 15, quad = lane >> 4;
    const int q0 = blockIdx.x * 64, bh = blockIdx.y;
    const int h = bh & 7, b = bh >> 3;
    const size_t tb = (size_t)bh * T_SEQ;
    const int ks0 = q0 - 128;

    // ---- phase 1: stage Q, K (+fused |k|^2) ----
    {
        const int row = tid >> 3, ch = tid & 7;
        f16x8 v = *(const f16x8*)(qh + (tb + q0 + row) * 64 + ch * 8);
        *(f16x8*)(Qs + row * 88 + ch * 8) = v;
    }
#pragma unroll
    for (int s = 0; s < 3; s++) {
        const int i = tid + 512 * s;
        const int row = i >> 3, ch = i & 7;
        const int kg = ks0 + row;
        f16x8 v = {};
        if (kg >= 0) v = *(const f16x8*)(kh + (tb + kg) * 64 + ch * 8);
        *(f16x8*)(Ks + row * 88 + ch * 8) = v;
        float ps = 0.f;
#pragma unroll
        for (int j = 0; j < 8; j++) { const float fv = (float)v[j]; ps += fv * fv; }
        ps += __shfl_xor(ps, 1);
        ps += __shfl_xor(ps, 2);
        ps += __shfl_xor(ps, 4);
        if (ch == 0) ksqs[row] = ps;
    }
    __syncthreads();   // B1

    // ---- phase 2: QK^T. wave = m-tile (w&3) x key-half (w>>2, 96 keys) ----
    const int mt  = w & 3;
    const int kh2 = w >> 2;
    f32x4 accQ[6];
#pragma unroll
    for (int jt = 0; jt < 6; jt++) accQ[jt] = (f32x4){0.f, 0.f, 0.f, 0.f};

    __builtin_amdgcn_s_setprio(1);
#pragma unroll
    for (int kp = 0; kp < 2; kp++) {
        const f16x8 af = *(const f16x8*)(Qs + (mt * 16 + lr) * 88 + kp * 32 + quad * 8);
#pragma unroll
        for (int jt = 0; jt < 6; jt++) {
            const f16x8 bf = *(const f16x8*)(Ks + (kh2 * 96 + jt * 16 + lr) * 88 + kp * 32 + quad * 8);
            accQ[jt] = __builtin_amdgcn_mfma_f32_16x16x32_f16(af, bf, accQ[jt], 0, 0, 0);
        }
    }
    __builtin_amdgcn_s_setprio(0);
    __syncthreads();   // B2: all Qs/Ks MFMA reads done -> Sc may alias them

    const float inv_s2 = __expf(-2.0f * logsig[h]);
#pragma unroll
    for (int jt = 0; jt < 6; jt++) {
        const int c  = kh2 * 96 + jt * 16 + lr;
        const float kq = ksqs[c];
        const int kg = ks0 + c;
#pragma unroll
        for (int r = 0; r < 4; r++) {
            const int dq = mt * 16 + quad * 4 + r;
            const unsigned wc = (unsigned)(c - dq - 1);
            if (wc < 128u) {
                Sc[dq * 132 + wc] = (kg >= 0) ? (accQ[jt][r] - 0.5f * kq) * inv_s2
                                              : -INFINITY;
            }
        }
    }

    // ---- T14: issue V^T global loads now; HBM latency hides under top-k ----
    f16x8 vpre[3];
#pragma unroll
    for (int s = 0; s < 3; s++) {
        const int i = tid + 512 * s;
        const int d = i / 24, ch = i % 24;
        const int t0v = ks0 + ch * 8;
        f16x8 vv = {};
        if (t0v >= 0) vv = *(const f16x8*)(vtg + ((size_t)bh * 64 + d) * T_SEQ + t0v);
        vpre[s] = vv;
    }
    __syncthreads();   // B3: Sc visible

    // ---- phase 3a: hoist ALL Sc reads to registers (static indices) ----
    const int wq8 = w * 8;
    unsigned u0[2][4], u1[2][4];
#pragma unroll
    for (int g = 0; g < 2; g++) {
#pragma unroll
        for (int qq = 0; qq < 4; qq++) {
            const int dq = wq8 + g * 4 + qq;
            const float s0 = Sc[dq * 132 + lane];
            const float s1 = Sc[dq * 132 + 64 + lane];
            const unsigned b0 = __float_as_uint(s0);
            const unsigned b1 = __float_as_uint(s1);
            u0[g][qq] = b0 ^ (unsigned)(((int)b0 >> 31) | 0x80000000);
            u1[g][qq] = b1 ^ (unsigned)(((int)b1 >> 31) | 0x80000000);
        }
    }
    __syncthreads();   // B4: all Sc reads done -> P/Vt may overwrite

    // ---- phase 4: write prefetched V^T (issues before the VALU search) ----
#pragma unroll
    for (int s = 0; s < 3; s++) {
        const int i = tid + 512 * s;
        const int d = i / 24, ch = i % 24;
        *(f16x8*)(Vt + d * 200 + ch * 8) = vpre[s];
    }

    // ---- phase 3b: exact top-96 ballot binary search — FULLY UNROLLED g
    //      (rule #20: static indices keep u0/u1 in registers) ----
#pragma unroll
    for (int g = 0; g < 2; g++) {
        unsigned t[4];
#pragma unroll
        for (int qq = 0; qq < 4; qq++) t[qq] = 0u;
#pragma unroll
        for (int bit = 31; bit >= 0; bit--) {
#pragma unroll
            for (int qq = 0; qq < 4; qq++) {
                const unsigned c = t[qq] | (1u << bit);
                const int n = __popcll(__ballot(u0[g][qq] >= c)) +
                              __popcll(__ballot(u1[g][qq] >= c));
                if (n >= TOPK) t[qq] = c;
            }
        }
#pragma unroll
        for (int qq = 0; qq < 4; qq++) {
            const int dq = wq8 + g * 4 + qq;
            const float p0 = (u0[g][qq] >= t[qq]) ? __expf(keyinv(u0[g][qq])) : 0.f;
            const float p1 = (u1[g][qq] >= t[qq]) ? __expf(keyinv(u1[g][qq])) : 0.f;
            P[dq * 200 + dq + 1 + lane]  = (f16)p0;
            P[dq * 200 + dq + 65 + lane] = (f16)p1;
            P[dq * 200 + ((lane <= dq) ? lane : lane + 128)] = (f16)0.f;
        }
    }
    __syncthreads();   // B5: P, Vt ready

    // ---- phase 5: PV MFMA + ones-MFMA row sums ----
    const int nh = w >> 2;
    f32x4 accO[2];
#pragma unroll
    for (int nt = 0; nt < 2; nt++) accO[nt] = (f32x4){0.f, 0.f, 0.f, 0.f};
    f32x4 accS = (f32x4){0.f, 0.f, 0.f, 0.f};
    f16x8 onesf;
#pragma unroll
    for (int j = 0; j < 8; j++) onesf[j] = (f16)1.0f;

    __builtin_amdgcn_s_setprio(1);
#pragma unroll
    for (int ks = 0; ks < 6; ks++) {
        const f16x8 pf = *(const f16x8*)(P + (mt * 16 + lr) * 200 + ks * 32 + quad * 8);
#pragma unroll
        for (int nt = 0; nt < 2; nt++) {
            const f16x8 vf = *(const f16x8*)(Vt + (nh * 32 + nt * 16 + lr) * 200 + ks * 32 + quad * 8);
            accO[nt] = __builtin_amdgcn_mfma_f32_16x16x32_f16(pf, vf, accO[nt], 0, 0, 0);
        }
        accS = __builtin_amdgcn_mfma_f32_16x16x32_f16(pf, onesf, accS, 0, 0, 0);
    }
    __builtin_amdgcn_s_setprio(0);
    float inv[4];
#pragma unroll
    for (int r = 0; r < 4; r++) inv[r] = 1.0f / accS[r];

#pragma unroll
    for (int nt = 0; nt < 2; nt++) {
        const int d = nh * 32 + nt * 16 + lr;
#pragma unroll
        for (int r = 0; r < 4; r++) {
            const int q = q0 + mt * 16 + quad * 4 + r;
            abh[((size_t)(b * T_SEQ + q)) * 512 + h * 64 + d] = (f16)(accO[nt][r] * inv[r]);
        }
    }
}

// ---------------------------------------------------------------------------
extern "C" void kernel_launch(void* const* d_in, const int* in_sizes, int n_in,
                              void* d_out, int out_size, void* d_ws, size_t ws_size,
                              hipStream_t stream)
{
    const float* x      = (const float*)d_in[0];
    const float* Wq     = (const float*)d_in[1];
    const float* bq     = (const float*)d_in[2];
    const float* Wk     = (const float*)d_in[3];
    const float* bk     = (const float*)d_in[4];
    const float* Wv     = (const float*)d_in[5];
    const float* bv     = (const float*)d_in[6];
    const float* Wo     = (const float*)d_in[7];
    const float* bo     = (const float*)d_in[8];
    const float* logsig = (const float*)d_in[9];

    f16* xh    = (f16*)d_ws;              // 4,194,304
    f16* wqkvh = xh + 4194304;            // 786,432
    f16* woh   = wqkvh + 786432;          // 262,144
    f16* qh    = woh + 262144;            // 4,194,304  [B,H,T,64]
    f16* kh    = qh + 4194304;            // 4,194,304  [B,H,T,64]
    f16* vtg   = kh + 4194304;            // 4,194,304  [B,H,64,T]
    f16* abh   = xh;                      // alias: x dead after QKV GEMM

    convert_all<<<5120, 256, 0, stream>>>(x, Wq, Wk, Wv, Wo, xh, wqkvh, woh);

    gemm_qkv<<<dim3(64, 12), 256, 0, stream>>>(xh, wqkvh, bq, bk, bv, qh, kh, vtg);

    attn_v8<<<dim3(T_SEQ / 64, BATCH * NHEADS), 512, 0, stream>>>(
        qh, kh, vtg, logsig, abh);

    gemm_o<<<dim3(64, 8), 256, 0, stream>>>(abh, woh, bo, (float*)d_out);
}